// Round 12
// baseline (125.733 us; speedup 1.0000x reference)
//
#include <hip/hip_runtime.h>

typedef _Float16 half4v __attribute__((ext_vector_type(4)));
typedef _Float16 h2     __attribute__((ext_vector_type(2)));
typedef float    float4v __attribute__((ext_vector_type(4)));

#define BB 16
#define CC 64
#define NN 4096   // H*W
#define MM 1024   // H*W/4
#define LN256 5.545177444479562f

static __device__ __forceinline__ float4v mfma16(half4v a, half4v b, float4v c) {
    return __builtin_amdgcn_mfma_f32_16x16x16f16(a, b, c, 0, 0, 0);
}

// fp32 pair -> packed fp16 pair (as u32)
__device__ __forceinline__ unsigned pk2(float a, float b) {
    union { _Float16 h[2]; unsigned u; } cv;
    cv.h[0] = (_Float16)a; cv.h[1] = (_Float16)b;
    return cv.u;
}
__device__ __forceinline__ h2 ash2(unsigned u) {
    union { unsigned u; h2 h; } c; c.u = u; return c.h;
}
__device__ __forceinline__ h2 hmax2(h2 a, h2 b) {
    h2 r;
    r.x = (a.x > b.x) ? a.x : b.x;
    r.y = (a.y > b.y) ? a.y : b.y;
    return r;
}
__device__ __forceinline__ h2 shfl_xor_h2(h2 v, int m) {
    union { h2 h; int i; } c; c.h = v; c.i = __shfl_xor(c.i, m);
    return c.h;
}

// ---------------------------------------------------------------------------
// Kernel 1 (unchanged, R10-proven): projections + fused 2x2 maxpool.
//   z=0: theta [B][N][8] + phi [B][M][8] (fp32 accum)
//   z=1: gT [B][32][M] via packed fp16 weights + v_pk_fma_f16
// ---------------------------------------------------------------------------
__global__ __launch_bounds__(128, 4) void proj_kernel(
    const float* __restrict__ x,      // [B][C][N]
    const float* __restrict__ w_th,   // [8][64]
    const float* __restrict__ w_ph,   // [8][64]
    const float* __restrict__ w_g,    // [32][64]
    _Float16* __restrict__ theta,     // [B][N][8]
    _Float16* __restrict__ phi,       // [B][M][8]
    _Float16* __restrict__ gT)        // [B][32][M]
{
    __shared__ __align__(16) float wlds[64 * 16];   // 4 KB (z1 reuses as u32)
    unsigned* wl2 = (unsigned*)wlds;

    const int b   = blockIdx.y;
    const int blk = blockIdx.x;
    const int z   = blockIdx.z;
    const int t   = threadIdx.x;

    if (z == 0) {
        for (int i = t; i < 1024; i += 128) {       // [c][o]: o<8 th, o<16 ph
            int c = i >> 4, o = i & 15;
            wlds[i] = (o < 8) ? w_th[o * 64 + c] : w_ph[(o - 8) * 64 + c];
        }
    } else {
        for (int i = t; i < 1024; i += 128) {       // [c][o2] h2 channel-pairs
            int c = i >> 4, o2 = i & 15;
            wl2[i] = pk2(w_g[(2 * o2) * 64 + c], w_g[(2 * o2 + 1) * 64 + c]);
        }
    }
    __syncthreads();

    const float2* x2 = (const float2*)(x + (size_t)b * CC * NN);
    const int p2 = blk * 128 + t;
    const int l = t & 63, w = t >> 6;
    const int m = (blk * 2 + w) * 32 + (l & 31);

    if (z == 0) {
        float th0[8], th1[8], ph0[8], ph1[8];
#pragma unroll
        for (int i = 0; i < 8; i++) { th0[i]=th1[i]=ph0[i]=ph1[i]=0.f; }
#pragma unroll 4
        for (int c = 0; c < 64; c++) {
            float2 xv = x2[c * (NN / 2) + p2];
            const float4* w4 = (const float4*)&wlds[c * 16];
            float4 wv[4];
#pragma unroll
            for (int j = 0; j < 4; j++) wv[j] = w4[j];
            const float* wf = (const float*)wv;
#pragma unroll
            for (int o = 0; o < 8; o++) {
                th0[o] = fmaf(wf[o], xv.x, th0[o]);
                th1[o] = fmaf(wf[o], xv.y, th1[o]);
                ph0[o] = fmaf(wf[8 + o], xv.x, ph0[o]);
                ph1[o] = fmaf(wf[8 + o], xv.y, ph1[o]);
            }
        }
        uint4* tw = (uint4*)(theta + ((size_t)b * NN + 2 * p2) * 8);
        tw[0] = make_uint4(pk2(th0[0],th0[1]), pk2(th0[2],th0[3]),
                           pk2(th0[4],th0[5]), pk2(th0[6],th0[7]));
        tw[1] = make_uint4(pk2(th1[0],th1[1]), pk2(th1[2],th1[3]),
                           pk2(th1[4],th1[5]), pk2(th1[6],th1[7]));
        float phm[8];
#pragma unroll
        for (int i = 0; i < 8; i++) phm[i] = fmaxf(ph0[i], ph1[i]);
#pragma unroll
        for (int i = 0; i < 8; i++) phm[i] = fmaxf(phm[i], __shfl_xor(phm[i], 32));
        if (l < 32) {
            uint4* pw = (uint4*)(phi + ((size_t)b * MM + m) * 8);
            pw[0] = make_uint4(pk2(phm[0],phm[1]), pk2(phm[2],phm[3]),
                               pk2(phm[4],phm[5]), pk2(phm[6],phm[7]));
        }
    } else {
        h2 ga[16], gb[16];
#pragma unroll
        for (int i = 0; i < 16; i++) { ga[i] = (h2)0; gb[i] = (h2)0; }
#pragma unroll 4
        for (int c = 0; c < 64; c++) {
            float2 xv = x2[c * (NN / 2) + p2];
            const uint4* w4 = (const uint4*)&wl2[c * 16];
            uint4 q0 = w4[0], q1 = w4[1], q2 = w4[2], q3 = w4[3];
            unsigned wv[16] = {q0.x,q0.y,q0.z,q0.w, q1.x,q1.y,q1.z,q1.w,
                               q2.x,q2.y,q2.z,q2.w, q3.x,q3.y,q3.z,q3.w};
            _Float16 hx = (_Float16)xv.x, hy = (_Float16)xv.y;
            h2 xa; xa.x = hx; xa.y = hx;
            h2 xb; xb.x = hy; xb.y = hy;
#pragma unroll
            for (int k = 0; k < 16; k++) {
                ga[k] = __builtin_elementwise_fma(ash2(wv[k]), xa, ga[k]);
                gb[k] = __builtin_elementwise_fma(ash2(wv[k]), xb, gb[k]);
            }
        }
        h2 gm[16];
#pragma unroll
        for (int k = 0; k < 16; k++) gm[k] = hmax2(ga[k], gb[k]);
#pragma unroll
        for (int k = 0; k < 16; k++) gm[k] = hmax2(gm[k], shfl_xor_h2(gm[k], 32));
        const int k0 = (l < 32) ? 0 : 8;
        _Float16* gp = gT + ((size_t)b * 32 + 2 * k0) * MM + m;
#pragma unroll
        for (int k = 0; k < 8; k++) {
            h2 v = gm[k0 + k];
            gp[(size_t)(2 * k) * MM]     = v.x;
            gp[(size_t)(2 * k + 1) * MM] = v.y;
        }
    }
}

// ---------------------------------------------------------------------------
// Kernel 2: fully-fused MFMA attention, SINGLE-PASS flash-online softmax
// on the R10-proven structure (16 n-cols/wave, 4 blocks/CU, 16 waves/CU).
// Per S-tile: tile-column max (3 fmax + shfl_xor 16/32), running-max update,
// accumulator rescale by alpha=exp(mx-nm), P = exp(s-nm+ln256).
// Invariants: P <= 256 (no fp16 overflow); global-max entry contributes
// exactly 256 to den (never down-rescaled) -> den >= 256 (no subnormal-
// flush zero-den). C-layout of P^T == B-operand layout -> O^T = gT.P^T
// chains in-register; ones-row A-frag gives the denominator; third MFMA
// applies w_o; epilogue adds x. LDS 24.5 KB.
// ---------------------------------------------------------------------------
__global__ __launch_bounds__(256, 4) void attn_kernel(
    const _Float16* __restrict__ theta,  // [B][N][8]
    const _Float16* __restrict__ phi,    // [B][M][8]
    const _Float16* __restrict__ gT,     // [B][32][M]
    const float* __restrict__ w_o,       // [64][32]
    const float* __restrict__ gamma_p,
    const float* __restrict__ x,         // [B][C][N]
    float* __restrict__ out)             // [B][C][N]
{
    __shared__ __align__(16) _Float16 phl[MM * 8];     // 16 KB, all of phi[b]
    __shared__ __align__(16) _Float16 gl[32 * 136];    // 8.5 KB (stride 136)

    const int b    = blockIdx.y;
    const int t    = threadIdx.x;
    const int wave = t >> 6;
    const int lane = t & 63;
    const int col  = lane & 15;       // n-col / c-row / co-row of frags
    const int q    = lane >> 4;       // quad
    const int nbase = blockIdx.x * 64 + wave * 16;

    const float4v zero4 = {0.f, 0.f, 0.f, 0.f};
    const half4v zeroh = {0, 0, 0, 0};

    // stage ALL of phi[b]: 1024 float4s
    {
        const float4* src = (const float4*)(phi + (size_t)b * MM * 8);
        float4* dst = (float4*)phl;
#pragma unroll
        for (int i = 0; i < 4; i++) dst[t + i * 256] = src[t + i * 256];
    }

    // theta B-frag for this wave's 16 n (k = q*4+j; k>=8 is zero pad)
    half4v thB = zeroh;
    if (q < 2)
        thB = *(const half4v*)(theta + ((size_t)b * NN + nbase + col) * 8 + q * 4);

    // ones A-frag: output row 0 = softmax denominator
    half4v onesA = zeroh;
    if (col == 0) {
        onesA[0] = (_Float16)1; onesA[1] = (_Float16)1;
        onesA[2] = (_Float16)1; onesA[3] = (_Float16)1;
    }

    __syncthreads();

    // ---- single pass: online max, P, O^T, denominator ----
    float mx = -1e30f;
    float4v acc0 = zero4, acc1 = zero4, accd = zero4;

    for (int m0 = 0; m0 < MM; m0 += 128) {
        __syncthreads();
        {
            int c = t >> 3, seg = (t & 7) * 16;
            const _Float16* src = gT + ((size_t)b * 32 + c) * MM + m0 + seg;
            float4 v0 = *(const float4*)src;
            float4 v1 = *(const float4*)(src + 8);
            *(float4*)&gl[c * 136 + seg]     = v0;
            *(float4*)&gl[c * 136 + seg + 8] = v1;
        }
        __syncthreads();

#pragma unroll 2
        for (int mt = 0; mt < 8; mt++) {
            // A-frag of phi: row = m-local = col, k = q*4+j (q>=2 -> zero)
            half4v af = zeroh;
            if (q < 2)
                af = *(const half4v*)&phl[(m0 + mt * 16 + col) * 8 + q * 4];
            float4v S = mfma16(af, thB, zero4);
            // S^T[m = m0 + mt*16 + q*4 + r][n = nbase + col]
            // tile-column max across the 4 quads sharing this column
            float tm = fmaxf(fmaxf(S.x, S.y), fmaxf(S.z, S.w));
            tm = fmaxf(tm, __shfl_xor(tm, 16));
            tm = fmaxf(tm, __shfl_xor(tm, 32));
            float nm = fmaxf(mx, tm);
            float alpha = __expf(mx - nm);   // first tile: exp(-huge) = 0
            mx = nm;
            acc0 *= alpha; acc1 *= alpha; accd *= alpha;
            const float base = nm - LN256;   // P = e^(s-nm) * 256 <= 256
            half4v P;
            P[0] = (_Float16)__expf(S.x - base);
            P[1] = (_Float16)__expf(S.y - base);
            P[2] = (_Float16)__expf(S.z - base);
            P[3] = (_Float16)__expf(S.w - base);
            // A-frags of gT: row = c-local = col, k = m-local = q*4+j
            half4v ag0 = *(const half4v*)&gl[col * 136 + mt * 16 + q * 4];
            half4v ag1 = *(const half4v*)&gl[(col + 16) * 136 + mt * 16 + q * 4];
            acc0 = mfma16(ag0, P, acc0);   // O^T c 0-15
            acc1 = mfma16(ag1, P, acc1);   // O^T c 16-31
            accd = mfma16(onesA, P, accd); // row 0 = denominator
        }
    }

    // denominator: accd row 0 lives on lanes 0-15 (q==0), element .x
    float dv = __shfl(accd.x, col);            // den[n] broadcast to all quads
    float sc = gamma_p[0] / dv;                // fold gamma into the scale

    // normalized O^T as B-frags for the w_o MFMA
    half4v B0, B1;
    B0[0] = (_Float16)(acc0.x * sc); B0[1] = (_Float16)(acc0.y * sc);
    B0[2] = (_Float16)(acc0.z * sc); B0[3] = (_Float16)(acc0.w * sc);
    B1[0] = (_Float16)(acc1.x * sc); B1[1] = (_Float16)(acc1.y * sc);
    B1[2] = (_Float16)(acc1.z * sc); B1[3] = (_Float16)(acc1.w * sc);

#pragma unroll
    for (int ct = 0; ct < 4; ct++) {
        // w_o A-frags: row = co-local = col, k = c = half*16 + q*4+j
        const float* wp = w_o + (size_t)(ct * 16 + col) * 32 + q * 4;
        float4 w0 = *(const float4*)wp;           // c 0-15 part
        float4 w1 = *(const float4*)(wp + 16);    // c 16-31 part
        half4v wa, wb;
        wa[0] = (_Float16)w0.x; wa[1] = (_Float16)w0.y;
        wa[2] = (_Float16)w0.z; wa[3] = (_Float16)w0.w;
        wb[0] = (_Float16)w1.x; wb[1] = (_Float16)w1.y;
        wb[2] = (_Float16)w1.z; wb[3] = (_Float16)w1.w;
        float4v D = mfma16(wa, B0, zero4);
        D = mfma16(wb, B1, D);
        // D[co-local = q*4+r][n = col]; out = D + x (gamma already in sc)
#pragma unroll
        for (int r = 0; r < 4; r++) {
            int co = ct * 16 + q * 4 + r;
            size_t idx = ((size_t)b * CC + co) * NN + nbase + col;
            out[idx] = D[r] + x[idx];
        }
    }
}

extern "C" void kernel_launch(void* const* d_in, const int* in_sizes, int n_in,
                              void* d_out, int out_size, void* d_ws, size_t ws_size,
                              hipStream_t stream) {
    const float* x       = (const float*)d_in[0];
    const float* w_theta = (const float*)d_in[1];
    const float* w_phi   = (const float*)d_in[2];
    const float* w_g     = (const float*)d_in[3];
    const float* w_o     = (const float*)d_in[4];
    const float* gamma   = (const float*)d_in[5];
    float* out = (float*)d_out;

    // fp16 workspace: theta [B][N][8], phi [B][M][8], gT [B][32][M] = 2.4 MB
    _Float16* theta_ws = (_Float16*)d_ws;
    _Float16* phi_ws   = theta_ws + (size_t)BB * NN * 8;
    _Float16* gT_ws    = phi_ws   + (size_t)BB * MM * 8;

    proj_kernel<<<dim3(16, BB, 2), 128, 0, stream>>>(
        x, w_theta, w_phi, w_g, theta_ws, phi_ws, gT_ws);

    attn_kernel<<<dim3(NN / 64, BB), 256, 0, stream>>>(
        theta_ws, phi_ws, gT_ws, w_o, gamma, x, out);
}

// Round 13
// 118.623 us; speedup vs baseline: 1.0599x; 1.0599x over previous
//
#include <hip/hip_runtime.h>

typedef _Float16 half4v __attribute__((ext_vector_type(4)));
typedef _Float16 h2     __attribute__((ext_vector_type(2)));
typedef float    float4v __attribute__((ext_vector_type(4)));

#define BB 16
#define CC 64
#define NN 4096   // H*W
#define MM 1024   // H*W/4
#define LN256 5.545177444479562f

static __device__ __forceinline__ float4v mfma16(half4v a, half4v b, float4v c) {
    return __builtin_amdgcn_mfma_f32_16x16x16f16(a, b, c, 0, 0, 0);
}

// fp32 pair -> packed fp16 pair (as u32)
__device__ __forceinline__ unsigned pk2(float a, float b) {
    union { _Float16 h[2]; unsigned u; } cv;
    cv.h[0] = (_Float16)a; cv.h[1] = (_Float16)b;
    return cv.u;
}
__device__ __forceinline__ h2 ash2(unsigned u) {
    union { unsigned u; h2 h; } c; c.u = u; return c.h;
}
__device__ __forceinline__ h2 hmax2(h2 a, h2 b) {
    h2 r;
    r.x = (a.x > b.x) ? a.x : b.x;
    r.y = (a.y > b.y) ? a.y : b.y;
    return r;
}
__device__ __forceinline__ h2 shfl_xor_h2(h2 v, int m) {
    union { h2 h; int i; } c; c.h = v; c.i = __shfl_xor(c.i, m);
    return c.h;
}

// ---------------------------------------------------------------------------
// Kernel 1 (unchanged, R10-proven): projections + fused 2x2 maxpool.
//   z=0: theta [B][N][8] + phi [B][M][8] (fp32 accum)
//   z=1: gT [B][32][M] via packed fp16 weights + v_pk_fma_f16
// ---------------------------------------------------------------------------
__global__ __launch_bounds__(128, 4) void proj_kernel(
    const float* __restrict__ x,      // [B][C][N]
    const float* __restrict__ w_th,   // [8][64]
    const float* __restrict__ w_ph,   // [8][64]
    const float* __restrict__ w_g,    // [32][64]
    _Float16* __restrict__ theta,     // [B][N][8]
    _Float16* __restrict__ phi,       // [B][M][8]
    _Float16* __restrict__ gT)        // [B][32][M]
{
    __shared__ __align__(16) float wlds[64 * 16];   // 4 KB (z1 reuses as u32)
    unsigned* wl2 = (unsigned*)wlds;

    const int b   = blockIdx.y;
    const int blk = blockIdx.x;
    const int z   = blockIdx.z;
    const int t   = threadIdx.x;

    if (z == 0) {
        for (int i = t; i < 1024; i += 128) {       // [c][o]: o<8 th, o<16 ph
            int c = i >> 4, o = i & 15;
            wlds[i] = (o < 8) ? w_th[o * 64 + c] : w_ph[(o - 8) * 64 + c];
        }
    } else {
        for (int i = t; i < 1024; i += 128) {       // [c][o2] h2 channel-pairs
            int c = i >> 4, o2 = i & 15;
            wl2[i] = pk2(w_g[(2 * o2) * 64 + c], w_g[(2 * o2 + 1) * 64 + c]);
        }
    }
    __syncthreads();

    const float2* x2 = (const float2*)(x + (size_t)b * CC * NN);
    const int p2 = blk * 128 + t;
    const int l = t & 63, w = t >> 6;
    const int m = (blk * 2 + w) * 32 + (l & 31);

    if (z == 0) {
        float th0[8], th1[8], ph0[8], ph1[8];
#pragma unroll
        for (int i = 0; i < 8; i++) { th0[i]=th1[i]=ph0[i]=ph1[i]=0.f; }
#pragma unroll 4
        for (int c = 0; c < 64; c++) {
            float2 xv = x2[c * (NN / 2) + p2];
            const float4* w4 = (const float4*)&wlds[c * 16];
            float4 wv[4];
#pragma unroll
            for (int j = 0; j < 4; j++) wv[j] = w4[j];
            const float* wf = (const float*)wv;
#pragma unroll
            for (int o = 0; o < 8; o++) {
                th0[o] = fmaf(wf[o], xv.x, th0[o]);
                th1[o] = fmaf(wf[o], xv.y, th1[o]);
                ph0[o] = fmaf(wf[8 + o], xv.x, ph0[o]);
                ph1[o] = fmaf(wf[8 + o], xv.y, ph1[o]);
            }
        }
        uint4* tw = (uint4*)(theta + ((size_t)b * NN + 2 * p2) * 8);
        tw[0] = make_uint4(pk2(th0[0],th0[1]), pk2(th0[2],th0[3]),
                           pk2(th0[4],th0[5]), pk2(th0[6],th0[7]));
        tw[1] = make_uint4(pk2(th1[0],th1[1]), pk2(th1[2],th1[3]),
                           pk2(th1[4],th1[5]), pk2(th1[6],th1[7]));
        float phm[8];
#pragma unroll
        for (int i = 0; i < 8; i++) phm[i] = fmaxf(ph0[i], ph1[i]);
#pragma unroll
        for (int i = 0; i < 8; i++) phm[i] = fmaxf(phm[i], __shfl_xor(phm[i], 32));
        if (l < 32) {
            uint4* pw = (uint4*)(phi + ((size_t)b * MM + m) * 8);
            pw[0] = make_uint4(pk2(phm[0],phm[1]), pk2(phm[2],phm[3]),
                               pk2(phm[4],phm[5]), pk2(phm[6],phm[7]));
        }
    } else {
        h2 ga[16], gb[16];
#pragma unroll
        for (int i = 0; i < 16; i++) { ga[i] = (h2)0; gb[i] = (h2)0; }
#pragma unroll 4
        for (int c = 0; c < 64; c++) {
            float2 xv = x2[c * (NN / 2) + p2];
            const uint4* w4 = (const uint4*)&wl2[c * 16];
            uint4 q0 = w4[0], q1 = w4[1], q2 = w4[2], q3 = w4[3];
            unsigned wv[16] = {q0.x,q0.y,q0.z,q0.w, q1.x,q1.y,q1.z,q1.w,
                               q2.x,q2.y,q2.z,q2.w, q3.x,q3.y,q3.z,q3.w};
            _Float16 hx = (_Float16)xv.x, hy = (_Float16)xv.y;
            h2 xa; xa.x = hx; xa.y = hx;
            h2 xb; xb.x = hy; xb.y = hy;
#pragma unroll
            for (int k = 0; k < 16; k++) {
                ga[k] = __builtin_elementwise_fma(ash2(wv[k]), xa, ga[k]);
                gb[k] = __builtin_elementwise_fma(ash2(wv[k]), xb, gb[k]);
            }
        }
        h2 gm[16];
#pragma unroll
        for (int k = 0; k < 16; k++) gm[k] = hmax2(ga[k], gb[k]);
#pragma unroll
        for (int k = 0; k < 16; k++) gm[k] = hmax2(gm[k], shfl_xor_h2(gm[k], 32));
        const int k0 = (l < 32) ? 0 : 8;
        _Float16* gp = gT + ((size_t)b * 32 + 2 * k0) * MM + m;
#pragma unroll
        for (int k = 0; k < 8; k++) {
            h2 v = gm[k0 + k];
            gp[(size_t)(2 * k) * MM]     = v.x;
            gp[(size_t)(2 * k + 1) * MM] = v.y;
        }
    }
}

// ---------------------------------------------------------------------------
// Kernel 2: R10-proven two-pass MFMA attention + double-buffered gT tiles.
// (R12's online softmax regressed: the per-tile fmax->shfl->rescale chain
// serializes between the S-MFMA and O-MFMAs. Two independent passes win.)
// All of phi[b] (16 KB) persists in LDS; pass 1 (max) is barrier-free.
// Pass 2: P = exp(s-mx+ln256) -> P_max = 256 (no fp16 overflow, no
// subnormal-flush zero-denominator). C-layout of P^T == B-operand layout ->
// O^T = gT.P^T chains in-register; ones-row A-frag gives the denominator;
// third MFMA applies w_o; epilogue adds x. gT staged into gl[2] (8.5 KB
// each): stage chunk i+1 while computing chunk i -> 1 barrier per chunk.
// LDS 33 KB -> 4 blocks/CU at (256,4); 16 waves/CU.
// ---------------------------------------------------------------------------
__global__ __launch_bounds__(256, 4) void attn_kernel(
    const _Float16* __restrict__ theta,  // [B][N][8]
    const _Float16* __restrict__ phi,    // [B][M][8]
    const _Float16* __restrict__ gT,     // [B][32][M]
    const float* __restrict__ w_o,       // [64][32]
    const float* __restrict__ gamma_p,
    const float* __restrict__ x,         // [B][C][N]
    float* __restrict__ out)             // [B][C][N]
{
    __shared__ __align__(16) _Float16 phl[MM * 8];       // 16 KB, all of phi[b]
    __shared__ __align__(16) _Float16 gl[2][32 * 136];   // 2 x 8.5 KB

    const int b    = blockIdx.y;
    const int t    = threadIdx.x;
    const int wave = t >> 6;
    const int lane = t & 63;
    const int col  = lane & 15;       // n-col / c-row / co-row of frags
    const int q    = lane >> 4;       // quad
    const int nbase = blockIdx.x * 64 + wave * 16;

    const float4v zero4 = {0.f, 0.f, 0.f, 0.f};
    const half4v zeroh = {0, 0, 0, 0};

    // stage ALL of phi[b]: 1024 float4s
    {
        const float4* src = (const float4*)(phi + (size_t)b * MM * 8);
        float4* dst = (float4*)phl;
#pragma unroll
        for (int i = 0; i < 4; i++) dst[t + i * 256] = src[t + i * 256];
    }

    // theta B-frag for this wave's 16 n (k = q*4+j; k>=8 is zero pad)
    half4v thB = zeroh;
    if (q < 2)
        thB = *(const half4v*)(theta + ((size_t)b * NN + nbase + col) * 8 + q * 4);

    // ones A-frag: output row 0 = softmax denominator
    half4v onesA = zeroh;
    if (col == 0) {
        onesA[0] = (_Float16)1; onesA[1] = (_Float16)1;
        onesA[2] = (_Float16)1; onesA[3] = (_Float16)1;
    }

    __syncthreads();

    // ---- pass 1: exact per-column score max (barrier-free) ----
    float mx = -1e30f;
#pragma unroll 4
    for (int mt = 0; mt < 64; mt++) {
        half4v af = zeroh;
        if (q < 2)
            af = *(const half4v*)&phl[(mt * 16 + col) * 8 + q * 4];
        float4v S = mfma16(af, thB, zero4);
        mx = fmaxf(mx, fmaxf(fmaxf(S.x, S.y), fmaxf(S.z, S.w)));
    }
    // reduce across the 4 quads that hold the same column (lane bits 4,5)
    mx = fmaxf(mx, __shfl_xor(mx, 16));
    mx = fmaxf(mx, __shfl_xor(mx, 32));
    const float shift = mx - LN256;   // P = e^(s-mx) * 256 <= 256

    // ---- pass 2: P, O^T, denominator (double-buffered gT tiles) ----
    float4v acc0 = zero4, acc1 = zero4, accd = zero4;

    const int sc_c = t >> 3, sc_s = (t & 7) * 16;   // staging coords
    // stage chunk 0 into gl[0]
    {
        const _Float16* src = gT + ((size_t)b * 32 + sc_c) * MM + sc_s;
        *(float4*)&gl[0][sc_c * 136 + sc_s]     = *(const float4*)src;
        *(float4*)&gl[0][sc_c * 136 + sc_s + 8] = *(const float4*)(src + 8);
    }
    __syncthreads();

    for (int c8 = 0; c8 < 8; c8++) {
        const int cur = c8 & 1;
        if (c8 < 7) {   // stage next chunk into the other buffer
            const _Float16* src =
                gT + ((size_t)b * 32 + sc_c) * MM + (c8 + 1) * 128 + sc_s;
            *(float4*)&gl[1 - cur][sc_c * 136 + sc_s]     = *(const float4*)src;
            *(float4*)&gl[1 - cur][sc_c * 136 + sc_s + 8] = *(const float4*)(src + 8);
        }

#pragma unroll 2
        for (int mt = 0; mt < 8; mt++) {
            // A-frag of phi: row = m-local = col, k = q*4+j (q>=2 -> zero)
            half4v af = zeroh;
            if (q < 2)
                af = *(const half4v*)&phl[(c8 * 128 + mt * 16 + col) * 8 + q * 4];
            float4v S = mfma16(af, thB, zero4);
            // S^T[m = c8*128 + mt*16 + q*4 + r][n = nbase + col]
            half4v P;
            P[0] = (_Float16)__expf(S.x - shift);
            P[1] = (_Float16)__expf(S.y - shift);
            P[2] = (_Float16)__expf(S.z - shift);
            P[3] = (_Float16)__expf(S.w - shift);
            // A-frags of gT: row = c-local = col, k = m-local = q*4+j
            half4v ag0 = *(const half4v*)&gl[cur][col * 136 + mt * 16 + q * 4];
            half4v ag1 = *(const half4v*)&gl[cur][(col + 16) * 136 + mt * 16 + q * 4];
            acc0 = mfma16(ag0, P, acc0);   // O^T c 0-15
            acc1 = mfma16(ag1, P, acc1);   // O^T c 16-31
            accd = mfma16(onesA, P, accd); // row 0 = denominator
        }
        __syncthreads();   // cur reads done; next-buffer writes visible
    }

    // denominator: accd row 0 lives on lanes 0-15 (q==0), element .x
    float dv = __shfl(accd.x, col);            // den[n] broadcast to all quads
    float sc = gamma_p[0] / dv;                // fold gamma into the scale

    // normalized O^T as B-frags for the w_o MFMA
    half4v B0, B1;
    B0[0] = (_Float16)(acc0.x * sc); B0[1] = (_Float16)(acc0.y * sc);
    B0[2] = (_Float16)(acc0.z * sc); B0[3] = (_Float16)(acc0.w * sc);
    B1[0] = (_Float16)(acc1.x * sc); B1[1] = (_Float16)(acc1.y * sc);
    B1[2] = (_Float16)(acc1.z * sc); B1[3] = (_Float16)(acc1.w * sc);

#pragma unroll
    for (int ct = 0; ct < 4; ct++) {
        // w_o A-frags: row = co-local = col, k = c = half*16 + q*4+j
        const float* wp = w_o + (size_t)(ct * 16 + col) * 32 + q * 4;
        float4 w0 = *(const float4*)wp;           // c 0-15 part
        float4 w1 = *(const float4*)(wp + 16);    // c 16-31 part
        half4v wa, wb;
        wa[0] = (_Float16)w0.x; wa[1] = (_Float16)w0.y;
        wa[2] = (_Float16)w0.z; wa[3] = (_Float16)w0.w;
        wb[0] = (_Float16)w1.x; wb[1] = (_Float16)w1.y;
        wb[2] = (_Float16)w1.z; wb[3] = (_Float16)w1.w;
        float4v D = mfma16(wa, B0, zero4);
        D = mfma16(wb, B1, D);
        // D[co-local = q*4+r][n = col]; out = D + x (gamma already in sc)
#pragma unroll
        for (int r = 0; r < 4; r++) {
            int co = ct * 16 + q * 4 + r;
            size_t idx = ((size_t)b * CC + co) * NN + nbase + col;
            out[idx] = D[r] + x[idx];
        }
    }
}

extern "C" void kernel_launch(void* const* d_in, const int* in_sizes, int n_in,
                              void* d_out, int out_size, void* d_ws, size_t ws_size,
                              hipStream_t stream) {
    const float* x       = (const float*)d_in[0];
    const float* w_theta = (const float*)d_in[1];
    const float* w_phi   = (const float*)d_in[2];
    const float* w_g     = (const float*)d_in[3];
    const float* w_o     = (const float*)d_in[4];
    const float* gamma   = (const float*)d_in[5];
    float* out = (float*)d_out;

    // fp16 workspace: theta [B][N][8], phi [B][M][8], gT [B][32][M] = 2.4 MB
    _Float16* theta_ws = (_Float16*)d_ws;
    _Float16* phi_ws   = theta_ws + (size_t)BB * NN * 8;
    _Float16* gT_ws    = phi_ws   + (size_t)BB * MM * 8;

    proj_kernel<<<dim3(16, BB, 2), 128, 0, stream>>>(
        x, w_theta, w_phi, w_g, theta_ws, phi_ws, gT_ws);

    attn_kernel<<<dim3(NN / 64, BB), 256, 0, stream>>>(
        theta_ws, phi_ws, gT_ws, w_o, gamma, x, out);
}